// Round 1
// baseline (399.990 us; speedup 1.0000x reference)
//
#include <hip/hip_runtime.h>

// Problem shape (fixed): B=4, T=2048, D=1024, fp32 in/out, bf16-tolerance threshold.
// Pipeline: cast/transposes -> QKV proj GEMMs -> scores (causal tile-skip) ->
//           row softmax -> PV (causal K-limit) -> output proj.
// All matmuls: bf16 MFMA 16x16x32, 128x128 tile, BK=32, global_load_lds width=16.

typedef __attribute__((ext_vector_type(8))) short short8;   // 8 bf16 = 4 VGPRs (MFMA A/B frag)
typedef __attribute__((ext_vector_type(4))) float f4;       // MFMA C/D frag

#define BM 128
#define BN 128
#define BK 32

__device__ inline unsigned short f2bf(float f) {
    union { float f; unsigned u; } c; c.f = f;
    unsigned u = c.u;
    return (unsigned short)((u + 0x7fffu + ((u >> 16) & 1u)) >> 16);  // RNE
}

__device__ inline void gload16(const void* g, void* l) {
    // async global->LDS, 16B/lane; LDS dest is wave-uniform base + lane*16
    __builtin_amdgcn_global_load_lds(
        (const __attribute__((address_space(1))) void*)g,
        (__attribute__((address_space(3))) void*)l,
        16, 0, 0);
}

// ---------------------------------------------------------------------------
// C = A[M,K] @ Bt[N,K]^T (+bias) ; A,Bt bf16(ushort), C fp32 or bf16.
// flags: bit0 = out bf16 ; bit1 = causal tile skip (scores) ; bit2 = causal K-limit (PV)
// lda = ldb = K, ldc = N. Batched via blockIdx.z with strides sA/sB/sC (elements).
// ---------------------------------------------------------------------------
__global__ __launch_bounds__(256)
void gemm_bt(const unsigned short* __restrict__ A,
             const unsigned short* __restrict__ Bt,
             void* __restrict__ C,
             const float* __restrict__ bias,
             int M, int N, int K,
             long sA, long sB, long sC,
             float scale, int flags)
{
    const int b = blockIdx.z;
    A  += (long)b * sA;
    Bt += (long)b * sB;

    const int m0 = blockIdx.y * BM;
    const int n0 = blockIdx.x * BN;

    if ((flags & 2) && n0 > m0 + (BM - 1)) return;   // fully-masked score tile

    int kend = K;
    if (flags & 4) { int ke = m0 + BM; kend = ke < K ? ke : K; }  // causal K-limit
    const int numK = kend / BK;

    __shared__ unsigned short As[BM * BK];   // 8 KB
    __shared__ unsigned short Bs[BN * BK];   // 8 KB

    const int tid  = threadIdx.x;
    const int lane = tid & 63;
    const int wave = tid >> 6;
    const int wm   = wave & 1;       // wave row in 2x2 wave grid (64 rows)
    const int wn   = wave >> 1;      // wave col (64 cols)
    const int lrow = lane & 15;
    const int quad = lane >> 4;

    f4 acc[4][4];
#pragma unroll
    for (int i = 0; i < 4; ++i)
#pragma unroll
        for (int j = 0; j < 4; ++j) acc[i][j] = (f4)0.0f;

    // staging geometry: tile is 128 rows x 32 cols bf16 = 128 x 64B = 512 chunks of 16B.
    // chunk e = r*256 + tid ; row = e>>2 ; col = (e&3)*8 ; LDS dest = base + e*16B.
    const int erow0 = tid >> 2;
    const int ecol  = (tid & 3) << 3;

    for (int kt = 0; kt < numK; ++kt) {
        const int k0 = kt * BK;
#pragma unroll
        for (int r = 0; r < 2; ++r) {
            const int row = r * 64 + erow0;           // (r*256+tid)>>2
            const unsigned short* ga = A  + (long)(m0 + row) * K + k0 + ecol;
            const unsigned short* gb = Bt + (long)(n0 + row) * K + k0 + ecol;
            const int ldsoff = (r * 256 + wave * 64) * 16;   // bytes, wave-uniform
            gload16(ga, (char*)As + ldsoff);
            gload16(gb, (char*)Bs + ldsoff);
        }
        __syncthreads();   // compiler emits s_waitcnt vmcnt(0) before barrier

        short8 af[4], bfr[4];
#pragma unroll
        for (int i = 0; i < 4; ++i) {
            af[i]  = *(const short8*)(As + (wm * 64 + i * 16 + lrow) * BK + quad * 8);
            bfr[i] = *(const short8*)(Bs + (wn * 64 + i * 16 + lrow) * BK + quad * 8);
        }
#pragma unroll
        for (int i = 0; i < 4; ++i)
#pragma unroll
            for (int j = 0; j < 4; ++j)
                acc[i][j] = __builtin_amdgcn_mfma_f32_16x16x32_bf16(af[i], bfr[j], acc[i][j], 0, 0, 0);
        __syncthreads();
    }

    // epilogue: C/D layout col=lane&15, row=quad*4+reg (verified m89/m91)
    const int  row0 = m0 + wm * 64 + quad * 4;
    const int  col0 = n0 + wn * 64 + lrow;
    const bool obf  = flags & 1;
    unsigned short* Cb = (unsigned short*)C;
    float*          Cf = (float*)C;
    const long cbase = (long)b * sC;

    float bj[4];
#pragma unroll
    for (int j = 0; j < 4; ++j) bj[j] = bias ? bias[col0 + j * 16] : 0.0f;

#pragma unroll
    for (int i = 0; i < 4; ++i) {
        const int row = row0 + i * 16;
#pragma unroll
        for (int j = 0; j < 4; ++j) {
            const int col = col0 + j * 16;
            const long off = cbase + (long)row * N + col;
#pragma unroll
            for (int r = 0; r < 4; ++r) {
                float v = acc[i][j][r] * scale + bj[j];
                if (obf) Cb[off + (long)r * N] = f2bf(v);
                else     Cf[off + (long)r * N] = v;
            }
        }
    }
}

// ---------------------------------------------------------------------------
// fp32 -> bf16 cast, 4 elems/thread
// ---------------------------------------------------------------------------
__global__ void cast_f32_bf16(const float* __restrict__ in,
                              unsigned short* __restrict__ out, int n4)
{
    int i = blockIdx.x * 256 + threadIdx.x;
    if (i >= n4) return;
    f4 v = ((const f4*)in)[i];
    unsigned long long p = (unsigned long long)f2bf(v.x)
                         | ((unsigned long long)f2bf(v.y) << 16)
                         | ((unsigned long long)f2bf(v.z) << 32)
                         | ((unsigned long long)f2bf(v.w) << 48);
    ((unsigned long long*)out)[i] = p;
}

// fp32 [R,C] -> bf16 [C,R]   (weights: W[k][n] -> Wt[n][k])
__global__ void transpose_cast(const float* __restrict__ in,
                               unsigned short* __restrict__ out, int R, int C)
{
    __shared__ unsigned short t[32][33];
    const int c0 = blockIdx.x * 32, r0 = blockIdx.y * 32;
    for (int i = threadIdx.y; i < 32; i += 8)
        t[i][threadIdx.x] = f2bf(in[(long)(r0 + i) * C + c0 + threadIdx.x]);
    __syncthreads();
    for (int i = threadIdx.y; i < 32; i += 8)
        out[(long)(c0 + i) * R + r0 + threadIdx.x] = t[threadIdx.x][i];
}

// bf16 [R,C] -> bf16 [C,R], batched (V -> V^T)
__global__ void transpose_bf16(const unsigned short* __restrict__ in,
                               unsigned short* __restrict__ out,
                               int R, int C, long sIn, long sOut)
{
    in  += (long)blockIdx.z * sIn;
    out += (long)blockIdx.z * sOut;
    __shared__ unsigned short t[32][33];
    const int c0 = blockIdx.x * 32, r0 = blockIdx.y * 32;
    for (int i = threadIdx.y; i < 32; i += 8)
        t[i][threadIdx.x] = in[(long)(r0 + i) * C + c0 + threadIdx.x];
    __syncthreads();
    for (int i = threadIdx.y; i < 32; i += 8)
        out[(long)(c0 + i) * R + r0 + threadIdx.x] = t[threadIdx.x][i];
}

// ---------------------------------------------------------------------------
// causal row softmax: S fp32 [B,T,T] -> P bf16 [B,T,T] (zeros above diagonal)
// one 256-thread block per row; row t has t+1 valid entries.
// ---------------------------------------------------------------------------
__global__ void softmax_causal(const float* __restrict__ S,
                               unsigned short* __restrict__ P, int T)
{
    const int t = blockIdx.x;
    const long rowoff = ((long)blockIdx.y * T + t) * T;
    const float* s = S + rowoff;
    unsigned short* p = P + rowoff;
    const int L = t + 1;
    const int tid = threadIdx.x;
    const int lane = tid & 63, wave = tid >> 6;
    __shared__ float red[4];

    float vals[8];   // T/256 == 8
    float m = -INFINITY;
#pragma unroll
    for (int it = 0; it < 8; ++it) {
        int i = it * 256 + tid;
        float v = (i < L) ? s[i] : -INFINITY;
        vals[it] = v;
        m = fmaxf(m, v);
    }
    for (int o = 32; o > 0; o >>= 1) m = fmaxf(m, __shfl_down(m, o));
    if (lane == 0) red[wave] = m;
    __syncthreads();
    m = fmaxf(fmaxf(red[0], red[1]), fmaxf(red[2], red[3]));
    __syncthreads();

    float sum = 0.0f;
#pragma unroll
    for (int it = 0; it < 8; ++it) {
        float e = __expf(vals[it] - m);   // exp(-inf - m) = 0
        vals[it] = e;
        sum += e;
    }
    for (int o = 32; o > 0; o >>= 1) sum += __shfl_down(sum, o);
    if (lane == 0) red[wave] = sum;
    __syncthreads();
    sum = red[0] + red[1] + red[2] + red[3];
    const float inv = 1.0f / sum;

#pragma unroll
    for (int it = 0; it < 8; ++it)
        p[it * 256 + tid] = f2bf(vals[it] * inv);
}

// ---------------------------------------------------------------------------
extern "C" void kernel_launch(void* const* d_in, const int* in_sizes, int n_in,
                              void* d_out, int out_size, void* d_ws, size_t ws_size,
                              hipStream_t stream)
{
    const float* x  = (const float*)d_in[0];
    const float* Wq = (const float*)d_in[1];
    const float* bq = (const float*)d_in[2];
    const float* Wk = (const float*)d_in[3];
    const float* bk = (const float*)d_in[4];
    const float* Wv = (const float*)d_in[5];
    const float* bv = (const float*)d_in[6];
    const float* Wh = (const float*)d_in[7];
    const float* bh = (const float*)d_in[8];
    float* out = (float*)d_out;

    const int  Bb = 4, T = 2048, Dm = 1024;
    const long BT = (long)Bb * T;          // 8192 rows

    // workspace carve (ushort units); total ~200 MB
    unsigned short* ws  = (unsigned short*)d_ws;
    size_t o = 0;
    unsigned short* Xbf = ws + o; o += (size_t)BT * Dm;        // 16 MB
    unsigned short* Wqt = ws + o; o += (size_t)Dm * Dm;        //  2 MB
    unsigned short* Wkt = ws + o; o += (size_t)Dm * Dm;
    unsigned short* Wvt = ws + o; o += (size_t)Dm * Dm;
    unsigned short* Wht = ws + o; o += (size_t)Dm * Dm;
    unsigned short* Qb  = ws + o; o += (size_t)BT * Dm;        // 16 MB
    unsigned short* Kb  = ws + o; o += (size_t)BT * Dm;
    unsigned short* Vb  = ws + o; o += (size_t)BT * Dm;
    unsigned short* Vt  = ws + o; o += (size_t)BT * Dm;
    float* S            = (float*)(ws + o); o += (size_t)Bb * T * T * 2;  // 64 MB fp32
    unsigned short* P   = ws + o; o += (size_t)Bb * T * T;     // 32 MB
    unsigned short* Ob  = ws + o;                              // 16 MB

    const dim3 blk(256);
    const dim3 tb(32, 8);

    // 1. cast x -> bf16
    cast_f32_bf16<<<(int)(BT * Dm / 4 / 256), blk, 0, stream>>>(x, Xbf, (int)(BT * Dm / 4));

    // 2. transpose+cast weights: W[k][n] -> Wt[n][k]
    transpose_cast<<<dim3(32, 32, 1), tb, 0, stream>>>(Wq, Wqt, Dm, Dm);
    transpose_cast<<<dim3(32, 32, 1), tb, 0, stream>>>(Wk, Wkt, Dm, Dm);
    transpose_cast<<<dim3(32, 32, 1), tb, 0, stream>>>(Wv, Wvt, Dm, Dm);
    transpose_cast<<<dim3(32, 32, 1), tb, 0, stream>>>(Wh, Wht, Dm, Dm);

    // 3. Q/K/V projections: [8192,1024] @ [1024,1024]^T + bias -> bf16
    gemm_bt<<<dim3(Dm / BN, BT / BM, 1), blk, 0, stream>>>(
        Xbf, Wqt, Qb, bq, (int)BT, Dm, Dm, 0, 0, 0, 1.0f, 1);
    gemm_bt<<<dim3(Dm / BN, BT / BM, 1), blk, 0, stream>>>(
        Xbf, Wkt, Kb, bk, (int)BT, Dm, Dm, 0, 0, 0, 1.0f, 1);
    gemm_bt<<<dim3(Dm / BN, BT / BM, 1), blk, 0, stream>>>(
        Xbf, Wvt, Vb, bv, (int)BT, Dm, Dm, 0, 0, 0, 1.0f, 1);

    // 4. V -> V^T per batch ([T,D] -> [D,T])
    transpose_bf16<<<dim3(Dm / 32, T / 32, Bb), tb, 0, stream>>>(
        Vb, Vt, T, Dm, (long)T * Dm, (long)Dm * T);

    // 5. scores = Q @ K^T * 1/sqrt(D), fp32, causal tile-skip
    gemm_bt<<<dim3(T / BN, T / BM, Bb), blk, 0, stream>>>(
        Qb, Kb, S, nullptr, T, T, Dm,
        (long)T * Dm, (long)T * Dm, (long)T * T, 1.0f / 32.0f, 2);

    // 6. causal softmax -> P bf16 (zeros above diagonal)
    softmax_causal<<<dim3(T, Bb), blk, 0, stream>>>(S, P, T);

    // 7. O = P @ V  (Bt = V^T), causal K-limit
    gemm_bt<<<dim3(Dm / BN, T / BM, Bb), blk, 0, stream>>>(
        P, Vt, Ob, nullptr, T, Dm, T,
        (long)T * T, (long)Dm * T, (long)T * Dm, 1.0f, 1 | 4);

    // 8. out = O @ Wh^T + bh, fp32 -> d_out
    gemm_bt<<<dim3(Dm / BN, BT / BM, 1), blk, 0, stream>>>(
        Ob, Wht, out, bh, (int)BT, Dm, Dm, 0, 0, 0, 1.0f, 0);
}

// Round 2
// 372.066 us; speedup vs baseline: 1.0751x; 1.0751x over previous
//
#include <hip/hip_runtime.h>

// B=4, T=2048, D=1024, fp32 in/out, bf16-tolerance threshold.
// Pipeline: cast x -> fused QKV GEMM (N=3072) -> V^T -> scores (bf16 S, causal
// tile-skip, reversed-y) -> softmax (bf16 in/out) -> PV (causal K-limit,
// reversed-y) -> output proj (fp32 out).
// GEMM: bf16 MFMA 16x16x32, 128x128 tile, BK=32, global_load_lds width=16.

typedef __attribute__((ext_vector_type(8))) short short8;   // MFMA A/B frag
typedef __attribute__((ext_vector_type(4))) float f4;       // MFMA C/D frag
typedef __attribute__((ext_vector_type(8))) unsigned short us8;

#define BM 128
#define BN 128
#define BK 32

__device__ inline unsigned short f2bf(float f) {
    union { float f; unsigned u; } c; c.f = f;
    unsigned u = c.u;
    return (unsigned short)((u + 0x7fffu + ((u >> 16) & 1u)) >> 16);  // RNE
}
__device__ inline float bf2f(unsigned short u) {
    union { unsigned u; float f; } c; c.u = ((unsigned)u) << 16;
    return c.f;
}

__device__ inline void gload16(const void* g, void* l) {
    __builtin_amdgcn_global_load_lds(
        (const __attribute__((address_space(1))) void*)g,
        (__attribute__((address_space(3))) void*)l,
        16, 0, 0);
}

// ---------------------------------------------------------------------------
// C = A[M,K] @ Bt[N,K]^T (+bias), bf16 in, fp32/bf16 out.
// flags: bit0 out-bf16 | bit1 causal tile-skip | bit2 causal K-limit | bit3 reverse-y
// ---------------------------------------------------------------------------
__global__ __launch_bounds__(256)
void gemm_bt(const unsigned short* __restrict__ A,
             const unsigned short* __restrict__ Bt,
             void* __restrict__ C,
             const float* __restrict__ bias,
             int M, int N, int K, int lda, int ldb, int ldc,
             long sA, long sB, long sC,
             float scale, int flags)
{
    const int b = blockIdx.z;
    A  += (long)b * sA;
    Bt += (long)b * sB;

    int by = blockIdx.y;
    if (flags & 8) by = gridDim.y - 1 - by;   // big-work blocks first (causal)
    const int m0 = by * BM;
    const int n0 = blockIdx.x * BN;

    if ((flags & 2) && n0 > m0 + (BM - 1)) return;   // fully-masked score tile

    int kend = K;
    if (flags & 4) { int ke = m0 + BM; kend = ke < K ? ke : K; }  // causal K-limit
    const int numK = kend / BK;

    __shared__ unsigned short As[BM * BK];   // 8 KB
    __shared__ unsigned short Bs[BN * BK];   // 8 KB

    const int tid  = threadIdx.x;
    const int lane = tid & 63;
    const int wave = tid >> 6;
    const int wm   = wave & 1;
    const int wn   = wave >> 1;
    const int lrow = lane & 15;
    const int quad = lane >> 4;

    f4 acc[4][4];
#pragma unroll
    for (int i = 0; i < 4; ++i)
#pragma unroll
        for (int j = 0; j < 4; ++j) acc[i][j] = (f4)0.0f;

    // staging: 128 rows x 64B; chunk e = r*256+tid; row=e>>2; col=(e&3)*8
    const int erow0 = tid >> 2;
    const int ecol  = (tid & 3) << 3;

    for (int kt = 0; kt < numK; ++kt) {
        const int k0 = kt * BK;
#pragma unroll
        for (int r = 0; r < 2; ++r) {
            const int row = r * 64 + erow0;
            const unsigned short* ga = A  + (long)(m0 + row) * lda + k0 + ecol;
            const unsigned short* gb = Bt + (long)(n0 + row) * ldb + k0 + ecol;
            const int ldsoff = (r * 256 + wave * 64) * 16;   // bytes, wave-uniform
            gload16(ga, (char*)As + ldsoff);
            gload16(gb, (char*)Bs + ldsoff);
        }
        __syncthreads();

        short8 af[4], bfr[4];
#pragma unroll
        for (int i = 0; i < 4; ++i) {
            af[i]  = *(const short8*)(As + (wm * 64 + i * 16 + lrow) * BK + quad * 8);
            bfr[i] = *(const short8*)(Bs + (wn * 64 + i * 16 + lrow) * BK + quad * 8);
        }
#pragma unroll
        for (int i = 0; i < 4; ++i)
#pragma unroll
            for (int j = 0; j < 4; ++j)
                acc[i][j] = __builtin_amdgcn_mfma_f32_16x16x32_bf16(af[i], bfr[j], acc[i][j], 0, 0, 0);
        __syncthreads();
    }

    // epilogue: C/D layout col=lane&15, row=quad*4+reg
    const int  row0 = m0 + wm * 64 + quad * 4;
    const int  col0 = n0 + wn * 64 + lrow;
    const bool obf  = flags & 1;
    unsigned short* Cb = (unsigned short*)C;
    float*          Cf = (float*)C;
    const long cbase = (long)b * sC;

    float bj[4];
#pragma unroll
    for (int j = 0; j < 4; ++j) bj[j] = bias ? bias[col0 + j * 16] : 0.0f;

#pragma unroll
    for (int i = 0; i < 4; ++i) {
        const int row = row0 + i * 16;
#pragma unroll
        for (int j = 0; j < 4; ++j) {
            const int col = col0 + j * 16;
            const long off = cbase + (long)row * ldc + col;
#pragma unroll
            for (int r = 0; r < 4; ++r) {
                float v = acc[i][j][r] * scale + bj[j];
                if (obf) Cb[off + (long)r * ldc] = f2bf(v);
                else     Cf[off + (long)r * ldc] = v;
            }
        }
    }
}

// ---------------------------------------------------------------------------
__global__ void cast_f32_bf16(const float* __restrict__ in,
                              unsigned short* __restrict__ out, int n4)
{
    int i = blockIdx.x * 256 + threadIdx.x;
    if (i >= n4) return;
    f4 v = ((const f4*)in)[i];
    unsigned long long p = (unsigned long long)f2bf(v.x)
                         | ((unsigned long long)f2bf(v.y) << 16)
                         | ((unsigned long long)f2bf(v.z) << 32)
                         | ((unsigned long long)f2bf(v.w) << 48);
    ((unsigned long long*)out)[i] = p;
}

// fp32 [R,C] -> bf16 [C,R]
__global__ void transpose_cast(const float* __restrict__ in,
                               unsigned short* __restrict__ out, int R, int C)
{
    __shared__ unsigned short t[32][33];
    const int c0 = blockIdx.x * 32, r0 = blockIdx.y * 32;
    for (int i = threadIdx.y; i < 32; i += 8)
        t[i][threadIdx.x] = f2bf(in[(long)(r0 + i) * C + c0 + threadIdx.x]);
    __syncthreads();
    for (int i = threadIdx.y; i < 32; i += 8)
        out[(long)(c0 + i) * R + r0 + threadIdx.x] = t[threadIdx.x][i];
}

// bf16 [R x C] (ldIn) -> bf16 [C x R] (ldOut), batched
__global__ void transpose_bf16(const unsigned short* __restrict__ in,
                               unsigned short* __restrict__ out,
                               int ldIn, int ldOut, long sIn, long sOut)
{
    in  += (long)blockIdx.z * sIn;
    out += (long)blockIdx.z * sOut;
    __shared__ unsigned short t[32][33];
    const int c0 = blockIdx.x * 32, r0 = blockIdx.y * 32;
    for (int i = threadIdx.y; i < 32; i += 8)
        t[i][threadIdx.x] = in[(long)(r0 + i) * ldIn + c0 + threadIdx.x];
    __syncthreads();
    for (int i = threadIdx.y; i < 32; i += 8)
        out[(long)(c0 + i) * ldOut + r0 + threadIdx.x] = t[threadIdx.x][i];
}

__global__ void concat3(const float* __restrict__ a, const float* __restrict__ b,
                        const float* __restrict__ c, float* __restrict__ o, int n)
{
    int i = blockIdx.x * 256 + threadIdx.x;
    if (i < n) { o[i] = a[i]; o[n + i] = b[i]; o[2 * n + i] = c[i]; }
}

// ---------------------------------------------------------------------------
// causal row softmax: S bf16 [B,T,T] -> P bf16 (zeros above diagonal)
// one 256-thread block per row; 8 contiguous elems/thread (16B ld/st)
// ---------------------------------------------------------------------------
__global__ void softmax_causal(const unsigned short* __restrict__ S,
                               unsigned short* __restrict__ P, int T)
{
    const int t = blockIdx.x;
    const long rowoff = ((long)blockIdx.y * T + t) * T;
    const int L = t + 1;
    const int tid = threadIdx.x;
    const int lane = tid & 63, wave = tid >> 6;
    __shared__ float red[4];

    us8 raw = *(const us8*)(S + rowoff + tid * 8);
    float vals[8];
    float m = -INFINITY;
    const int i0 = tid * 8;
#pragma unroll
    for (int k = 0; k < 8; ++k) {
        float v = (i0 + k < L) ? bf2f(raw[k]) : -INFINITY;
        vals[k] = v;
        m = fmaxf(m, v);
    }
    for (int o = 32; o > 0; o >>= 1) m = fmaxf(m, __shfl_down(m, o));
    if (lane == 0) red[wave] = m;
    __syncthreads();
    m = fmaxf(fmaxf(red[0], red[1]), fmaxf(red[2], red[3]));
    __syncthreads();

    float sum = 0.0f;
#pragma unroll
    for (int k = 0; k < 8; ++k) {
        float e = __expf(vals[k] - m);
        vals[k] = e;
        sum += e;
    }
    for (int o = 32; o > 0; o >>= 1) sum += __shfl_down(sum, o);
    if (lane == 0) red[wave] = sum;
    __syncthreads();
    sum = red[0] + red[1] + red[2] + red[3];
    const float inv = 1.0f / sum;

    us8 outp;
#pragma unroll
    for (int k = 0; k < 8; ++k) outp[k] = f2bf(vals[k] * inv);
    *(us8*)(P + rowoff + i0) = outp;
}

// ---------------------------------------------------------------------------
extern "C" void kernel_launch(void* const* d_in, const int* in_sizes, int n_in,
                              void* d_out, int out_size, void* d_ws, size_t ws_size,
                              hipStream_t stream)
{
    const float* x  = (const float*)d_in[0];
    const float* Wq = (const float*)d_in[1];
    const float* bq = (const float*)d_in[2];
    const float* Wk = (const float*)d_in[3];
    const float* bk = (const float*)d_in[4];
    const float* Wv = (const float*)d_in[5];
    const float* bv = (const float*)d_in[6];
    const float* Wh = (const float*)d_in[7];
    const float* bh = (const float*)d_in[8];
    float* out = (float*)d_out;

    const int  Bb = 4, T = 2048, Dm = 1024;
    const long BT = (long)Bb * T;          // 8192

    // workspace carve (ushort units), ~170 MB total
    unsigned short* ws = (unsigned short*)d_ws;
    size_t o = 0;
    unsigned short* Xbf   = ws + o; o += (size_t)BT * Dm;          // 16 MB
    unsigned short* Wqkvt = ws + o; o += (size_t)3 * Dm * Dm;      //  6 MB
    unsigned short* Wht   = ws + o; o += (size_t)Dm * Dm;          //  2 MB
    float* bqkv = (float*)(ws + o); o += (size_t)3 * Dm * 2;       // 12 KB
    unsigned short* QKV   = ws + o; o += (size_t)BT * 3 * Dm;      // 48 MB
    unsigned short* Vt    = ws + o; o += (size_t)BT * Dm;          // 16 MB
    unsigned short* S     = ws + o; o += (size_t)Bb * T * T;       // 32 MB
    unsigned short* P     = ws + o; o += (size_t)Bb * T * T;       // 32 MB
    unsigned short* Ob    = ws + o;                                // 16 MB

    const dim3 blk(256);
    const dim3 tb(32, 8);
    const long sRow3 = (long)T * 3 * Dm;   // batch stride in QKV

    // 1. cast x -> bf16; concat biases
    cast_f32_bf16<<<(int)(BT * Dm / 4 / 256), blk, 0, stream>>>(x, Xbf, (int)(BT * Dm / 4));
    concat3<<<4, blk, 0, stream>>>(bq, bk, bv, bqkv, Dm);

    // 2. transpose+cast weights into concatenated [3072,1024] (and Wh -> [1024,1024])
    transpose_cast<<<dim3(32, 32, 1), tb, 0, stream>>>(Wq, Wqkvt,               Dm, Dm);
    transpose_cast<<<dim3(32, 32, 1), tb, 0, stream>>>(Wk, Wqkvt + Dm * Dm,     Dm, Dm);
    transpose_cast<<<dim3(32, 32, 1), tb, 0, stream>>>(Wv, Wqkvt + 2 * Dm * Dm, Dm, Dm);
    transpose_cast<<<dim3(32, 32, 1), tb, 0, stream>>>(Wh, Wht,                 Dm, Dm);

    // 3. fused QKV projection: [8192,1024] @ [3072,1024]^T + bias -> QKV bf16
    gemm_bt<<<dim3(3 * Dm / BN, BT / BM, 1), blk, 0, stream>>>(
        Xbf, Wqkvt, QKV, bqkv, (int)BT, 3 * Dm, Dm, Dm, Dm, 3 * Dm,
        0, 0, 0, 1.0f, 1);

    // 4. V -> V^T per batch ([T, D] view stride 3072 -> [D, T])
    transpose_bf16<<<dim3(Dm / 32, T / 32, Bb), tb, 0, stream>>>(
        QKV + 2 * Dm, Vt, 3 * Dm, T, sRow3, (long)Dm * T);

    // 5. scores = Q @ K^T * 1/sqrt(D) -> bf16, causal tile-skip, reversed-y
    gemm_bt<<<dim3(T / BN, T / BM, Bb), blk, 0, stream>>>(
        QKV, QKV + Dm, S, nullptr, T, T, Dm, 3 * Dm, 3 * Dm, T,
        sRow3, sRow3, (long)T * T, 1.0f / 32.0f, 1 | 2 | 8);

    // 6. causal softmax -> P bf16 (zeros above diagonal)
    softmax_causal<<<dim3(T, Bb), blk, 0, stream>>>(S, P, T);

    // 7. O = P @ V^T, causal K-limit, reversed-y
    gemm_bt<<<dim3(Dm / BN, T / BM, Bb), blk, 0, stream>>>(
        P, Vt, Ob, nullptr, T, Dm, T, T, T, Dm,
        (long)T * T, (long)Dm * T, (long)T * Dm, 1.0f, 1 | 4 | 8);

    // 8. out = O @ Wh^T + bh -> fp32 d_out
    gemm_bt<<<dim3(Dm / BN, BT / BM, 1), blk, 0, stream>>>(
        Ob, Wht, out, bh, (int)BT, Dm, Dm, Dm, Dm, Dm,
        0, 0, 0, 1.0f, 0);
}